// Round 2
// baseline (852.709 us; speedup 1.0000x reference)
//
#include <hip/hip_runtime.h>
#include <hip/hip_bf16.h>

#define N_NODES 65536
#define DIM 512
#define N_EDGES 524288
#define BN_EPS 1e-5f
#define NORM_EPS 1e-6f

typedef __attribute__((ext_vector_type(8))) short short8;
typedef __attribute__((ext_vector_type(4))) float f32x4;

static __device__ __forceinline__ unsigned f2bf(float f) {
    union { float f; unsigned u; } c; c.f = f;
    unsigned u = c.u;
    return (u + 0x7fffu + ((u >> 16) & 1u)) >> 16;
}

static __device__ __forceinline__ uint4 pack8(float4 a, float4 b) {
    uint4 o;
    o.x = f2bf(a.x) | (f2bf(a.y) << 16);
    o.y = f2bf(a.z) | (f2bf(a.w) << 16);
    o.z = f2bf(b.x) | (f2bf(b.y) << 16);
    o.w = f2bf(b.z) | (f2bf(b.w) << 16);
    return o;
}

// ---------------- CSR build ----------------
__global__ void hist_kernel(const int* __restrict__ src, int* __restrict__ counts) {
    int e = blockIdx.x * blockDim.x + threadIdx.x;
    if (e < N_EDGES) atomicAdd(&counts[src[e]], 1);
}

__global__ void scan_kernel(const int* __restrict__ counts,
                            int* __restrict__ offsets, int* __restrict__ cursor) {
    __shared__ int lds[1024];
    int t = threadIdx.x;
    int base = t * 64;
    int s = 0;
    for (int i = 0; i < 64; ++i) s += counts[base + i];
    lds[t] = s;
    __syncthreads();
    for (int d = 1; d < 1024; d <<= 1) {
        int v = lds[t];
        int add = (t >= d) ? lds[t - d] : 0;
        __syncthreads();
        lds[t] = v + add;
        __syncthreads();
    }
    if (t == 1023) offsets[N_NODES] = lds[1023];
    int run = (t == 0) ? 0 : lds[t - 1];
    for (int i = 0; i < 64; ++i) {
        offsets[base + i] = run;
        cursor[base + i] = run;
        run += counts[base + i];
    }
}

__global__ void scatter_kernel(const int* __restrict__ src, const int* __restrict__ tgt,
                               int* __restrict__ cursor, int* __restrict__ sortedT) {
    int e = blockIdx.x * blockDim.x + threadIdx.x;
    if (e < N_EDGES) {
        int s = src[e];
        int pos = atomicAdd(&cursor[s], 1);
        sortedT[pos] = tgt[e];
    }
}

// ---------------- neighbor aggregation (wave per node) ----------------
// features fp32 [N,512]; lane handles 8 cols; fp32 accum; emit bf16 agg.
__global__ void aggregate_kernel(const float* __restrict__ features,
                                 const int* __restrict__ offsets,
                                 const int* __restrict__ sortedT,
                                 unsigned short* __restrict__ agg) {
    int wave = (blockIdx.x * blockDim.x + threadIdx.x) >> 6;
    int lane = threadIdx.x & 63;
    if (wave >= N_NODES) return;
    int beg = offsets[wave], end = offsets[wave + 1];
    float4 a0 = {0.f, 0.f, 0.f, 0.f}, a1 = {0.f, 0.f, 0.f, 0.f};
    const float4* F = (const float4*)features;
    for (int i = beg; i < end; ++i) {
        int t = sortedT[i];
        float4 v0 = F[t * 128 + lane * 2];
        float4 v1 = F[t * 128 + lane * 2 + 1];
        a0.x += v0.x; a0.y += v0.y; a0.z += v0.z; a0.w += v0.w;
        a1.x += v1.x; a1.y += v1.y; a1.z += v1.z; a1.w += v1.w;
    }
    ((uint4*)agg)[wave * 64 + lane] = pack8(a0, a1);
}

// ---------------- fused GEMM + bias + ReLU + BN (pre-norm) ----------------
// C[m,n] = relu( sum_k Xcat[m,k]*W[n,k] + b[n] ) -> BN affine -> fp32 out
// 128x128 tile, BK=64, 4 waves x 64x64 subtile, 16x16x32 bf16 MFMA.
// A first half / B staged from fp32 with on-the-fly bf16 convert.
__global__ __launch_bounds__(256) void gemm_kernel(
        const float* __restrict__ features,
        const unsigned short* __restrict__ agg,
        const float* __restrict__ W,
        const float* __restrict__ bias,
        const float* __restrict__ gamma,
        const float* __restrict__ beta,
        const float* __restrict__ rmean,
        const float* __restrict__ rvar,
        float* __restrict__ out) {
    __shared__ uint4 Alds[128 * 8];   // 128 rows x 64 bf16, XOR-swizzled chunks
    __shared__ uint4 Blds[128 * 8];

    const int t = threadIdx.x;
    const int m0 = blockIdx.x * 128;
    const int n0 = blockIdx.y * 128;
    const int w = t >> 6, L = t & 63;
    const int wm = (w >> 1) * 64, wn = (w & 1) * 64;
    const int ml = L & 15, quad = L >> 4;

    f32x4 acc[4][4];
#pragma unroll
    for (int mi = 0; mi < 4; ++mi)
#pragma unroll
        for (int ni = 0; ni < 4; ++ni)
            acc[mi][ni] = (f32x4){0.f, 0.f, 0.f, 0.f};

    for (int kt = 0; kt < 16; ++kt) {
        __syncthreads();
#pragma unroll
        for (int i = 0; i < 4; ++i) {
            int c = i * 256 + t;
            int r = c >> 3, p = c & 7;
            // A tile
            uint4 va;
            if (kt < 8) {
                const float* ap = features + (m0 + r) * 512 + kt * 64 + p * 8;
                float4 f0 = *(const float4*)ap;
                float4 f1 = *(const float4*)(ap + 4);
                va = pack8(f0, f1);
            } else {
                va = *(const uint4*)(agg + (m0 + r) * 512 + (kt - 8) * 64 + p * 8);
            }
            Alds[r * 8 + (p ^ (r & 7))] = va;
            // B tile (W fp32, row stride 1024)
            const float* bp = W + (n0 + r) * 1024 + kt * 64 + p * 8;
            float4 g0 = *(const float4*)bp;
            float4 g1 = *(const float4*)(bp + 4);
            Blds[r * 8 + (p ^ (r & 7))] = pack8(g0, g1);
        }
        __syncthreads();
#pragma unroll
        for (int kc = 0; kc < 2; ++kc) {
            int g = kc * 4 + quad;
            short8 a[4], b[4];
#pragma unroll
            for (int mi = 0; mi < 4; ++mi) {
                int ra = wm + mi * 16 + ml;
                a[mi] = *(const short8*)&Alds[ra * 8 + (g ^ (ra & 7))];
                int rb = wn + mi * 16 + ml;
                b[mi] = *(const short8*)&Blds[rb * 8 + (g ^ (rb & 7))];
            }
#pragma unroll
            for (int mi = 0; mi < 4; ++mi)
#pragma unroll
                for (int ni = 0; ni < 4; ++ni)
                    acc[mi][ni] = __builtin_amdgcn_mfma_f32_16x16x32_bf16(
                        a[mi], b[ni], acc[mi][ni], 0, 0, 0);
        }
    }

    // epilogue: bias -> relu -> BN affine, fp32 store (pre-norm)
#pragma unroll
    for (int ni = 0; ni < 4; ++ni) {
        int col = n0 + wn + ni * 16 + ml;
        float bi = bias[col];
        float sc = gamma[col] * __frsqrt_rn(rvar[col] + BN_EPS);
        float sh = beta[col] - rmean[col] * sc;
#pragma unroll
        for (int mi = 0; mi < 4; ++mi) {
#pragma unroll
            for (int r = 0; r < 4; ++r) {
                int m = m0 + wm + mi * 16 + quad * 4 + r;
                float v = acc[mi][ni][r] + bi;
                v = fmaxf(v, 0.f) * sc + sh;
                out[m * 512 + col] = v;
            }
        }
    }
}

// ---------------- row L2 normalize (wave per node, in place, fp32) ----------------
__global__ void normalize_kernel(float* __restrict__ out) {
    int wave = (blockIdx.x * blockDim.x + threadIdx.x) >> 6;
    int lane = threadIdx.x & 63;
    if (wave >= N_NODES) return;
    float4* O = (float4*)out;
    int base = wave * 128 + lane * 2;
    float4 v0 = O[base], v1 = O[base + 1];
    float ss = v0.x * v0.x + v0.y * v0.y + v0.z * v0.z + v0.w * v0.w
             + v1.x * v1.x + v1.y * v1.y + v1.z * v1.z + v1.w * v1.w;
#pragma unroll
    for (int d = 1; d < 64; d <<= 1) ss += __shfl_xor(ss, d);
    float inv = 1.f / (sqrtf(ss) + NORM_EPS);
    v0.x *= inv; v0.y *= inv; v0.z *= inv; v0.w *= inv;
    v1.x *= inv; v1.y *= inv; v1.z *= inv; v1.w *= inv;
    O[base] = v0;
    O[base + 1] = v1;
}

extern "C" void kernel_launch(void* const* d_in, const int* in_sizes, int n_in,
                              void* d_out, int out_size, void* d_ws, size_t ws_size,
                              hipStream_t stream) {
    const float* features = (const float*)d_in[0];
    const int* edges      = (const int*)d_in[1];
    const float* W        = (const float*)d_in[2];
    const float* bias     = (const float*)d_in[3];
    const float* gamma    = (const float*)d_in[4];
    const float* beta     = (const float*)d_in[5];
    const float* rmean    = (const float*)d_in[6];
    const float* rvar     = (const float*)d_in[7];
    float* out = (float*)d_out;

    char* ws = (char*)d_ws;
    int* counts  = (int*)(ws);                 // 256 KB
    int* offsets = (int*)(ws + 0x41000);       // 256 KB + 4
    int* cursor  = (int*)(ws + 0x82000);       // 256 KB
    int* sortedT = (int*)(ws + 0xC3000);       // 2 MB
    unsigned short* agg = (unsigned short*)(ws + 0x300000);  // 64 MB bf16

    const int* src = edges;
    const int* tgt = edges + N_EDGES;

    hipMemsetAsync(counts, 0, N_NODES * sizeof(int), stream);
    hist_kernel<<<N_EDGES / 256, 256, 0, stream>>>(src, counts);
    scan_kernel<<<1, 1024, 0, stream>>>(counts, offsets, cursor);
    scatter_kernel<<<N_EDGES / 256, 256, 0, stream>>>(src, tgt, cursor, sortedT);
    aggregate_kernel<<<N_NODES / 4, 256, 0, stream>>>(features, offsets, sortedT, agg);
    dim3 grid_gemm(N_NODES / 128, 4);
    gemm_kernel<<<grid_gemm, 256, 0, stream>>>(features, agg, W, bias, gamma, beta,
                                               rmean, rvar, out);
    normalize_kernel<<<N_NODES / 4, 256, 0, stream>>>(out);
}

// Round 3
// 637.788 us; speedup vs baseline: 1.3370x; 1.3370x over previous
//
#include <hip/hip_runtime.h>
#include <hip/hip_bf16.h>

#define N_NODES 65536
#define DIM 512
#define N_EDGES 524288
#define BN_EPS 1e-5f
#define NORM_EPS 1e-6f

typedef __attribute__((ext_vector_type(8))) short short8;
typedef __attribute__((ext_vector_type(4))) float f32x4;

static __device__ __forceinline__ unsigned f2bf(float f) {
    union { float f; unsigned u; } c; c.f = f;
    unsigned u = c.u;
    return (u + 0x7fffu + ((u >> 16) & 1u)) >> 16;
}
static __device__ __forceinline__ float bf16lo(unsigned u) {
    union { unsigned u; float f; } c; c.u = u << 16; return c.f;
}
static __device__ __forceinline__ float bf16hi(unsigned u) {
    union { unsigned u; float f; } c; c.u = u & 0xffff0000u; return c.f;
}
static __device__ __forceinline__ uint4 pack8(float4 a, float4 b) {
    uint4 o;
    o.x = f2bf(a.x) | (f2bf(a.y) << 16);
    o.y = f2bf(a.z) | (f2bf(a.w) << 16);
    o.z = f2bf(b.x) | (f2bf(b.y) << 16);
    o.w = f2bf(b.z) | (f2bf(b.w) << 16);
    return o;
}

// ---------------- fp32 -> bf16 convert (8 elems/thread) ----------------
__global__ void convert_kernel(const float* __restrict__ src,
                               unsigned short* __restrict__ dst, int n8) {
    int i = blockIdx.x * blockDim.x + threadIdx.x;
    if (i < n8) {
        const float4* s = (const float4*)src + i * 2;
        float4 f0 = s[0], f1 = s[1];
        ((uint4*)dst)[i] = pack8(f0, f1);
    }
}

// ---------------- CSR build ----------------
__global__ void hist_kernel(const int* __restrict__ src, int* __restrict__ counts) {
    int e = blockIdx.x * blockDim.x + threadIdx.x;
    if (e < N_EDGES) atomicAdd(&counts[src[e]], 1);
}

__global__ void scan_kernel(const int* __restrict__ counts,
                            int* __restrict__ offsets, int* __restrict__ cursor) {
    __shared__ int lds[1024];
    int t = threadIdx.x;
    int base = t * 64;
    int s = 0;
    for (int i = 0; i < 64; ++i) s += counts[base + i];
    lds[t] = s;
    __syncthreads();
    for (int d = 1; d < 1024; d <<= 1) {
        int v = lds[t];
        int add = (t >= d) ? lds[t - d] : 0;
        __syncthreads();
        lds[t] = v + add;
        __syncthreads();
    }
    if (t == 1023) offsets[N_NODES] = lds[1023];
    int run = (t == 0) ? 0 : lds[t - 1];
    for (int i = 0; i < 64; ++i) {
        offsets[base + i] = run;
        cursor[base + i] = run;
        run += counts[base + i];
    }
}

__global__ void scatter_kernel(const int* __restrict__ src, const int* __restrict__ tgt,
                               int* __restrict__ cursor, int* __restrict__ sortedT) {
    int e = blockIdx.x * blockDim.x + threadIdx.x;
    if (e < N_EDGES) {
        int s = src[e];
        int pos = atomicAdd(&cursor[s], 1);
        sortedT[pos] = tgt[e];
    }
}

// ---------------- neighbor aggregation (wave per node, bf16 gather) ----------------
__global__ void aggregate_kernel(const unsigned short* __restrict__ Xb,
                                 const int* __restrict__ offsets,
                                 const int* __restrict__ sortedT,
                                 unsigned short* __restrict__ agg) {
    int wave = (blockIdx.x * blockDim.x + threadIdx.x) >> 6;
    int lane = threadIdx.x & 63;
    if (wave >= N_NODES) return;
    int beg = offsets[wave], end = offsets[wave + 1];
    float a[8] = {0.f, 0.f, 0.f, 0.f, 0.f, 0.f, 0.f, 0.f};
    const uint4* F = (const uint4*)Xb;
    for (int i = beg; i < end; ++i) {
        int t = sortedT[i];
        uint4 v = F[t * 64 + lane];
        a[0] += bf16lo(v.x); a[1] += bf16hi(v.x);
        a[2] += bf16lo(v.y); a[3] += bf16hi(v.y);
        a[4] += bf16lo(v.z); a[5] += bf16hi(v.z);
        a[6] += bf16lo(v.w); a[7] += bf16hi(v.w);
    }
    uint4 o;
    o.x = f2bf(a[0]) | (f2bf(a[1]) << 16);
    o.y = f2bf(a[2]) | (f2bf(a[3]) << 16);
    o.z = f2bf(a[4]) | (f2bf(a[5]) << 16);
    o.w = f2bf(a[6]) | (f2bf(a[7]) << 16);
    ((uint4*)agg)[wave * 64 + lane] = o;
}

// ---------------- fused GEMM + bias + ReLU + BN (pre-norm) ----------------
// All-bf16 inputs; global_load_lds (width 16) staging with source-address
// XOR permutation so the LDS image matches the validated swizzled read path.
__global__ __launch_bounds__(256) void gemm_kernel(
        const unsigned short* __restrict__ Xb,    // [N,512] bf16
        const unsigned short* __restrict__ agg,   // [N,512] bf16
        const unsigned short* __restrict__ Wb,    // [512,1024] bf16
        const float* __restrict__ bias,
        const float* __restrict__ gamma,
        const float* __restrict__ beta,
        const float* __restrict__ rmean,
        const float* __restrict__ rvar,
        float* __restrict__ out) {
    __shared__ uint4 Alds[1024];   // 128 rows x 8 chunks(16B), XOR-swizzled image
    __shared__ uint4 Blds[1024];

    const int t = threadIdx.x;
    const int n0 = blockIdx.x * 128;   // x = n fastest: 4 n-blocks share A slab in L2
    const int m0 = blockIdx.y * 128;
    const int w = t >> 6, L = t & 63;
    const int wm = (w >> 1) * 64, wn = (w & 1) * 64;
    const int ml = L & 15, quad = L >> 4;

    f32x4 acc[4][4];
#pragma unroll
    for (int mi = 0; mi < 4; ++mi)
#pragma unroll
        for (int ni = 0; ni < 4; ++ni)
            acc[mi][ni] = (f32x4){0.f, 0.f, 0.f, 0.f};

    for (int kt = 0; kt < 16; ++kt) {
        const unsigned short* Asrc = (kt < 8) ? (Xb + kt * 64) : (agg + (kt - 8) * 64);
        const unsigned short* Bsrc = Wb + kt * 64;
        __syncthreads();
#pragma unroll
        for (int i = 0; i < 4; ++i) {
            int c = i * 256 + t;
            int r = c >> 3, pp = c & 7;
            int p = pp ^ (r & 7);            // permuted source chunk -> swizzled LDS image
            const unsigned short* ga = Asrc + (m0 + r) * 512 + p * 8;
            const unsigned short* gb = Bsrc + (n0 + r) * 1024 + p * 8;
            char* la = (char*)Alds + (i * 256 + (t & 192)) * 16;  // wave-uniform base
            char* lb = (char*)Blds + (i * 256 + (t & 192)) * 16;
            __builtin_amdgcn_global_load_lds(
                (const __attribute__((address_space(1))) unsigned int*)ga,
                (__attribute__((address_space(3))) unsigned int*)la, 16, 0, 0);
            __builtin_amdgcn_global_load_lds(
                (const __attribute__((address_space(1))) unsigned int*)gb,
                (__attribute__((address_space(3))) unsigned int*)lb, 16, 0, 0);
        }
        __syncthreads();
#pragma unroll
        for (int kc = 0; kc < 2; ++kc) {
            int g = kc * 4 + quad;
            short8 a[4], b[4];
#pragma unroll
            for (int mi = 0; mi < 4; ++mi) {
                int ra = wm + mi * 16 + ml;
                a[mi] = *(const short8*)&Alds[ra * 8 + (g ^ (ra & 7))];
                int rb = wn + mi * 16 + ml;
                b[mi] = *(const short8*)&Blds[rb * 8 + (g ^ (rb & 7))];
            }
#pragma unroll
            for (int mi = 0; mi < 4; ++mi)
#pragma unroll
                for (int ni = 0; ni < 4; ++ni)
                    acc[mi][ni] = __builtin_amdgcn_mfma_f32_16x16x32_bf16(
                        a[mi], b[ni], acc[mi][ni], 0, 0, 0);
        }
    }

    // epilogue: bias -> relu -> BN affine, fp32 store (pre-norm)
#pragma unroll
    for (int ni = 0; ni < 4; ++ni) {
        int col = n0 + wn + ni * 16 + ml;
        float bi = bias[col];
        float sc = gamma[col] * __frsqrt_rn(rvar[col] + BN_EPS);
        float sh = beta[col] - rmean[col] * sc;
#pragma unroll
        for (int mi = 0; mi < 4; ++mi) {
#pragma unroll
            for (int r = 0; r < 4; ++r) {
                int m = m0 + wm + mi * 16 + quad * 4 + r;
                float v = acc[mi][ni][r] + bi;
                v = fmaxf(v, 0.f) * sc + sh;
                out[m * 512 + col] = v;
            }
        }
    }
}

// ---------------- row L2 normalize (wave per node, in place, fp32) ----------------
__global__ void normalize_kernel(float* __restrict__ out) {
    int wave = (blockIdx.x * blockDim.x + threadIdx.x) >> 6;
    int lane = threadIdx.x & 63;
    if (wave >= N_NODES) return;
    float4* O = (float4*)out;
    int base = wave * 128 + lane * 2;
    float4 v0 = O[base], v1 = O[base + 1];
    float ss = v0.x * v0.x + v0.y * v0.y + v0.z * v0.z + v0.w * v0.w
             + v1.x * v1.x + v1.y * v1.y + v1.z * v1.z + v1.w * v1.w;
#pragma unroll
    for (int d = 1; d < 64; d <<= 1) ss += __shfl_xor(ss, d);
    float inv = 1.f / (sqrtf(ss) + NORM_EPS);
    v0.x *= inv; v0.y *= inv; v0.z *= inv; v0.w *= inv;
    v1.x *= inv; v1.y *= inv; v1.z *= inv; v1.w *= inv;
    O[base] = v0;
    O[base + 1] = v1;
}

extern "C" void kernel_launch(void* const* d_in, const int* in_sizes, int n_in,
                              void* d_out, int out_size, void* d_ws, size_t ws_size,
                              hipStream_t stream) {
    const float* features = (const float*)d_in[0];
    const int* edges      = (const int*)d_in[1];
    const float* W        = (const float*)d_in[2];
    const float* bias     = (const float*)d_in[3];
    const float* gamma    = (const float*)d_in[4];
    const float* beta     = (const float*)d_in[5];
    const float* rmean    = (const float*)d_in[6];
    const float* rvar     = (const float*)d_in[7];
    float* out = (float*)d_out;

    char* ws = (char*)d_ws;
    int* counts  = (int*)(ws);                              // 256 KB
    int* offsets = (int*)(ws + 0x100000);                   // 256 KB + 4
    int* cursor  = (int*)(ws + 0x200000);                   // 256 KB
    int* sortedT = (int*)(ws + 0x300000);                   // 2 MB
    unsigned short* Wb  = (unsigned short*)(ws + 0x500000); // 1 MB bf16 W
    unsigned short* Xb  = (unsigned short*)(ws + 0x600000); // 64 MB bf16 features
    unsigned short* agg = (unsigned short*)(ws + 0x4600000);// 64 MB bf16 aggregated

    const int* src = edges;
    const int* tgt = edges + N_EDGES;

    hipMemsetAsync(counts, 0, N_NODES * sizeof(int), stream);
    hist_kernel<<<N_EDGES / 256, 256, 0, stream>>>(src, counts);
    scan_kernel<<<1, 1024, 0, stream>>>(counts, offsets, cursor);
    scatter_kernel<<<N_EDGES / 256, 256, 0, stream>>>(src, tgt, cursor, sortedT);
    convert_kernel<<<(N_NODES * DIM / 8) / 256, 256, 0, stream>>>(features, Xb, N_NODES * DIM / 8);
    convert_kernel<<<(DIM * 2 * DIM / 8) / 256, 256, 0, stream>>>(W, Wb, DIM * 2 * DIM / 8);
    aggregate_kernel<<<N_NODES / 4, 256, 0, stream>>>(Xb, offsets, sortedT, agg);
    dim3 grid_gemm(4, N_NODES / 128);
    gemm_kernel<<<grid_gemm, 256, 0, stream>>>(Xb, agg, Wb, bias, gamma, beta,
                                               rmean, rvar, out);
    normalize_kernel<<<N_NODES / 4, 256, 0, stream>>>(out);
}

// Round 4
// 513.357 us; speedup vs baseline: 1.6610x; 1.2424x over previous
//
#include <hip/hip_runtime.h>
#include <hip/hip_bf16.h>

#define N_NODES 65536
#define DIM 512
#define N_EDGES 524288
#define BN_EPS 1e-5f
#define NORM_EPS 1e-6f

typedef __attribute__((ext_vector_type(8))) short short8;
typedef __attribute__((ext_vector_type(4))) float f32x4;

static __device__ __forceinline__ unsigned f2bf(float f) {
    union { float f; unsigned u; } c; c.f = f;
    unsigned u = c.u;
    return (u + 0x7fffu + ((u >> 16) & 1u)) >> 16;
}
static __device__ __forceinline__ float bf16lo(unsigned u) {
    union { unsigned u; float f; } c; c.u = u << 16; return c.f;
}
static __device__ __forceinline__ float bf16hi(unsigned u) {
    union { unsigned u; float f; } c; c.u = u & 0xffff0000u; return c.f;
}
static __device__ __forceinline__ uint4 pack8(float4 a, float4 b) {
    uint4 o;
    o.x = f2bf(a.x) | (f2bf(a.y) << 16);
    o.y = f2bf(a.z) | (f2bf(a.w) << 16);
    o.z = f2bf(b.x) | (f2bf(b.y) << 16);
    o.w = f2bf(b.z) | (f2bf(b.w) << 16);
    return o;
}

// ---------------- fp32 -> bf16 convert (8 elems/thread) ----------------
__global__ void convert_kernel(const float* __restrict__ src,
                               unsigned short* __restrict__ dst, int n8) {
    int i = blockIdx.x * blockDim.x + threadIdx.x;
    if (i < n8) {
        const float4* s = (const float4*)src + i * 2;
        float4 f0 = s[0], f1 = s[1];
        ((uint4*)dst)[i] = pack8(f0, f1);
    }
}

// ---------------- CSR build ----------------
__global__ void hist_kernel(const int* __restrict__ src, int* __restrict__ counts) {
    int e = blockIdx.x * blockDim.x + threadIdx.x;
    if (e < N_EDGES) atomicAdd(&counts[src[e]], 1);
}

// stage 1: per-block (256 counts) sums
__global__ void scan_partial(const int* __restrict__ counts, int* __restrict__ partials) {
    __shared__ int ws[4];
    int t = threadIdx.x;
    int v = counts[blockIdx.x * 256 + t];
#pragma unroll
    for (int d = 1; d < 64; d <<= 1) v += __shfl_xor(v, d);
    if ((t & 63) == 0) ws[t >> 6] = v;
    __syncthreads();
    if (t == 0) partials[blockIdx.x] = ws[0] + ws[1] + ws[2] + ws[3];
}

// stage 2: exclusive scan of the 256 partials (in place), single block
__global__ void scan_base(int* __restrict__ partials) {
    __shared__ int lds[256];
    int t = threadIdx.x;
    int v = partials[t];
    lds[t] = v;
    __syncthreads();
    for (int d = 1; d < 256; d <<= 1) {
        int mine = lds[t];
        int add = (t >= d) ? lds[t - d] : 0;
        __syncthreads();
        lds[t] = mine + add;
        __syncthreads();
    }
    partials[t] = lds[t] - v;   // exclusive
}

// stage 3: block-local exclusive scan + base -> offsets & cursor
__global__ void scan_final(const int* __restrict__ counts,
                           const int* __restrict__ partials,
                           int* __restrict__ offsets, int* __restrict__ cursor) {
    __shared__ int lds[256];
    int t = threadIdx.x, b = blockIdx.x;
    int v = counts[b * 256 + t];
    lds[t] = v;
    __syncthreads();
    for (int d = 1; d < 256; d <<= 1) {
        int mine = lds[t];
        int add = (t >= d) ? lds[t - d] : 0;
        __syncthreads();
        lds[t] = mine + add;
        __syncthreads();
    }
    int excl = lds[t] - v + partials[b];
    offsets[b * 256 + t] = excl;
    cursor[b * 256 + t] = excl;
    if (b == 255 && t == 255) offsets[N_NODES] = excl + v;   // == N_EDGES
}

__global__ void scatter_kernel(const int* __restrict__ src, const int* __restrict__ tgt,
                               int* __restrict__ cursor, int* __restrict__ sortedT) {
    int e = blockIdx.x * blockDim.x + threadIdx.x;
    if (e < N_EDGES) {
        int s = src[e];
        int pos = atomicAdd(&cursor[s], 1);
        sortedT[pos] = tgt[e];
    }
}

// ---------------- neighbor aggregation (wave per node, bf16 gather) ----------------
__global__ void aggregate_kernel(const unsigned short* __restrict__ Xb,
                                 const int* __restrict__ offsets,
                                 const int* __restrict__ sortedT,
                                 unsigned short* __restrict__ agg) {
    int wave = (blockIdx.x * blockDim.x + threadIdx.x) >> 6;
    int lane = threadIdx.x & 63;
    if (wave >= N_NODES) return;
    int beg = offsets[wave], end = offsets[wave + 1];
    float a[8] = {0.f, 0.f, 0.f, 0.f, 0.f, 0.f, 0.f, 0.f};
    const uint4* F = (const uint4*)Xb;
    for (int i = beg; i < end; ++i) {
        int t = sortedT[i];
        uint4 v = F[t * 64 + lane];
        a[0] += bf16lo(v.x); a[1] += bf16hi(v.x);
        a[2] += bf16lo(v.y); a[3] += bf16hi(v.y);
        a[4] += bf16lo(v.z); a[5] += bf16hi(v.z);
        a[6] += bf16lo(v.w); a[7] += bf16hi(v.w);
    }
    uint4 o;
    o.x = f2bf(a[0]) | (f2bf(a[1]) << 16);
    o.y = f2bf(a[2]) | (f2bf(a[3]) << 16);
    o.z = f2bf(a[4]) | (f2bf(a[5]) << 16);
    o.w = f2bf(a[6]) | (f2bf(a[7]) << 16);
    ((uint4*)agg)[wave * 64 + lane] = o;
}

// ---------------- fused GEMM + bias + ReLU + BN (pre-norm) ----------------
__global__ __launch_bounds__(256) void gemm_kernel(
        const unsigned short* __restrict__ Xb,    // [N,512] bf16
        const unsigned short* __restrict__ agg,   // [N,512] bf16
        const unsigned short* __restrict__ Wb,    // [512,1024] bf16
        const float* __restrict__ bias,
        const float* __restrict__ gamma,
        const float* __restrict__ beta,
        const float* __restrict__ rmean,
        const float* __restrict__ rvar,
        float* __restrict__ out) {
    __shared__ uint4 Alds[1024];   // 128 rows x 8 chunks(16B), XOR-swizzled image
    __shared__ uint4 Blds[1024];

    const int t = threadIdx.x;
    const int n0 = blockIdx.x * 128;
    const int m0 = blockIdx.y * 128;
    const int w = t >> 6, L = t & 63;
    const int wm = (w >> 1) * 64, wn = (w & 1) * 64;
    const int ml = L & 15, quad = L >> 4;

    f32x4 acc[4][4];
#pragma unroll
    for (int mi = 0; mi < 4; ++mi)
#pragma unroll
        for (int ni = 0; ni < 4; ++ni)
            acc[mi][ni] = (f32x4){0.f, 0.f, 0.f, 0.f};

    for (int kt = 0; kt < 16; ++kt) {
        const unsigned short* Asrc = (kt < 8) ? (Xb + kt * 64) : (agg + (kt - 8) * 64);
        const unsigned short* Bsrc = Wb + kt * 64;
        __syncthreads();
#pragma unroll
        for (int i = 0; i < 4; ++i) {
            int c = i * 256 + t;
            int r = c >> 3, pp = c & 7;
            int p = pp ^ (r & 7);            // permuted source chunk -> swizzled LDS image
            const unsigned short* ga = Asrc + (m0 + r) * 512 + p * 8;
            const unsigned short* gb = Bsrc + (n0 + r) * 1024 + p * 8;
            char* la = (char*)Alds + (i * 256 + (t & 192)) * 16;  // wave-uniform base
            char* lb = (char*)Blds + (i * 256 + (t & 192)) * 16;
            __builtin_amdgcn_global_load_lds(
                (const __attribute__((address_space(1))) unsigned int*)ga,
                (__attribute__((address_space(3))) unsigned int*)la, 16, 0, 0);
            __builtin_amdgcn_global_load_lds(
                (const __attribute__((address_space(1))) unsigned int*)gb,
                (__attribute__((address_space(3))) unsigned int*)lb, 16, 0, 0);
        }
        __syncthreads();
#pragma unroll
        for (int kc = 0; kc < 2; ++kc) {
            int g = kc * 4 + quad;
            short8 a[4], b[4];
#pragma unroll
            for (int mi = 0; mi < 4; ++mi) {
                int ra = wm + mi * 16 + ml;
                a[mi] = *(const short8*)&Alds[ra * 8 + (g ^ (ra & 7))];
                int rb = wn + mi * 16 + ml;
                b[mi] = *(const short8*)&Blds[rb * 8 + (g ^ (rb & 7))];
            }
#pragma unroll
            for (int mi = 0; mi < 4; ++mi)
#pragma unroll
                for (int ni = 0; ni < 4; ++ni)
                    acc[mi][ni] = __builtin_amdgcn_mfma_f32_16x16x32_bf16(
                        a[mi], b[ni], acc[mi][ni], 0, 0, 0);
        }
    }

#pragma unroll
    for (int ni = 0; ni < 4; ++ni) {
        int col = n0 + wn + ni * 16 + ml;
        float bi = bias[col];
        float sc = gamma[col] * __frsqrt_rn(rvar[col] + BN_EPS);
        float sh = beta[col] - rmean[col] * sc;
#pragma unroll
        for (int mi = 0; mi < 4; ++mi) {
#pragma unroll
            for (int r = 0; r < 4; ++r) {
                int m = m0 + wm + mi * 16 + quad * 4 + r;
                float v = acc[mi][ni][r] + bi;
                v = fmaxf(v, 0.f) * sc + sh;
                out[m * 512 + col] = v;
            }
        }
    }
}

// ---------------- row L2 normalize (wave per node, in place, fp32) ----------------
__global__ void normalize_kernel(float* __restrict__ out) {
    int wave = (blockIdx.x * blockDim.x + threadIdx.x) >> 6;
    int lane = threadIdx.x & 63;
    if (wave >= N_NODES) return;
    float4* O = (float4*)out;
    int base = wave * 128 + lane * 2;
    float4 v0 = O[base], v1 = O[base + 1];
    float ss = v0.x * v0.x + v0.y * v0.y + v0.z * v0.z + v0.w * v0.w
             + v1.x * v1.x + v1.y * v1.y + v1.z * v1.z + v1.w * v1.w;
#pragma unroll
    for (int d = 1; d < 64; d <<= 1) ss += __shfl_xor(ss, d);
    float inv = 1.f / (sqrtf(ss) + NORM_EPS);
    v0.x *= inv; v0.y *= inv; v0.z *= inv; v0.w *= inv;
    v1.x *= inv; v1.y *= inv; v1.z *= inv; v1.w *= inv;
    O[base] = v0;
    O[base + 1] = v1;
}

extern "C" void kernel_launch(void* const* d_in, const int* in_sizes, int n_in,
                              void* d_out, int out_size, void* d_ws, size_t ws_size,
                              hipStream_t stream) {
    const float* features = (const float*)d_in[0];
    const int* edges      = (const int*)d_in[1];
    const float* W        = (const float*)d_in[2];
    const float* bias     = (const float*)d_in[3];
    const float* gamma    = (const float*)d_in[4];
    const float* beta     = (const float*)d_in[5];
    const float* rmean    = (const float*)d_in[6];
    const float* rvar     = (const float*)d_in[7];
    float* out = (float*)d_out;

    char* ws = (char*)d_ws;
    int* counts   = (int*)(ws);                              // 256 KB
    int* offsets  = (int*)(ws + 0x100000);                   // 256 KB + 4
    int* cursor   = (int*)(ws + 0x200000);                   // 256 KB
    int* partials = (int*)(ws + 0x280000);                   // 1 KB
    int* sortedT  = (int*)(ws + 0x300000);                   // 2 MB
    unsigned short* Wb  = (unsigned short*)(ws + 0x500000);  // 1 MB bf16 W
    unsigned short* Xb  = (unsigned short*)(ws + 0x600000);  // 64 MB bf16 features
    unsigned short* agg = (unsigned short*)(ws + 0x4600000); // 64 MB bf16 aggregated

    const int* src = edges;
    const int* tgt = edges + N_EDGES;

    hipMemsetAsync(counts, 0, N_NODES * sizeof(int), stream);
    hist_kernel<<<N_EDGES / 256, 256, 0, stream>>>(src, counts);
    scan_partial<<<256, 256, 0, stream>>>(counts, partials);
    scan_base<<<1, 256, 0, stream>>>(partials);
    scan_final<<<256, 256, 0, stream>>>(counts, partials, offsets, cursor);
    scatter_kernel<<<N_EDGES / 256, 256, 0, stream>>>(src, tgt, cursor, sortedT);
    convert_kernel<<<(N_NODES * DIM / 8) / 256, 256, 0, stream>>>(features, Xb, N_NODES * DIM / 8);
    convert_kernel<<<(DIM * 2 * DIM / 8) / 256, 256, 0, stream>>>(W, Wb, DIM * 2 * DIM / 8);
    aggregate_kernel<<<N_NODES / 4, 256, 0, stream>>>(Xb, offsets, sortedT, agg);
    dim3 grid_gemm(4, N_NODES / 128);
    gemm_kernel<<<grid_gemm, 256, 0, stream>>>(Xb, agg, Wb, bias, gamma, beta,
                                               rmean, rvar, out);
    normalize_kernel<<<N_NODES / 4, 256, 0, stream>>>(out);
}